// Round 3
// baseline (9645.557 us; speedup 1.0000x reference)
//
#include <hip/hip_runtime.h>

#define BATCH 8
#define N 32768
#define NPOINT 2048
#define NT 1024              // threads per block (16 waves)
#define NG 8                 // f4 groups per thread: NT*NG*4 == N

typedef __attribute__((ext_vector_type(4))) float f4;

#define REP8(M)  M(0) M(1) M(2) M(3) M(4) M(5) M(6) M(7)
#define REP8R(M) M(7) M(6) M(5) M(4) M(3) M(2) M(1) M(0)

// One block per batch. All point state (x,y,z,temp) lives in registers:
// 32 f4 = 128 VGPRs/thread at NT=1024 -> fits arch VGPRs, no AGPR shuttling,
// no LDS reads in the hot loop. One barrier per iteration: packed 64-bit
// LDS atomicMax of (dist_bits<<32 | N-idx) does max + lowest-index tiebreak.
// Bit-exact numpy semantics: contract off, (xx+yy)+zz order, lowest-index ties.

__global__ __attribute__((amdgpu_flat_work_group_size(NT, NT),
                          amdgpu_waves_per_eu(4, 4)))
void fps_kernel(const float* __restrict__ pts_t,  // (B,3,N)
                float* __restrict__ out)          // (B,3,NPOINT)
{
#pragma clang fp contract(off)
    __shared__ unsigned long long s_key[NPOINT];  // 16 KiB, one slot per iter

    const int b = blockIdx.x;
    const int t = threadIdx.x;

    const float* __restrict__ px = pts_t + (size_t)b * 3 * N;
    const float* __restrict__ py = px + N;
    const float* __restrict__ pz = py + N;
    const f4* __restrict__ px4 = (const f4*)px;
    const f4* __restrict__ py4 = (const f4*)py;
    const f4* __restrict__ pz4 = (const f4*)pz;
    float* outx = out + (size_t)b * 3 * NPOINT;
    float* outy = outx + NPOINT;
    float* outz = outy + NPOINT;

    // ---- 32 named f4 registers: x, y, z, temp (4 points per group-lane) ----
#define DECL(g) f4 X##g, Y##g, Z##g, T##g;
    REP8(DECL)
#undef DECL

#define LOADG(g) { const int Q = (g) * NT + t;                    \
                   X##g = px4[Q]; Y##g = py4[Q]; Z##g = pz4[Q];   \
                   T##g = (f4){1e10f, 1e10f, 1e10f, 1e10f}; }
    REP8(LOADG)
#undef LOADG

    // zero the per-iteration key slots
    s_key[t] = 0ull;
    s_key[t + NT] = 0ull;

    // First selected index is 0 (reference: idx[0] = 0).
    float lx = px[0], ly = py[0], lz = pz[0];
    if (t == 0) { outx[0] = lx; outy[0] = ly; outz[0] = lz; }
    __syncthreads();

    for (int j = 1; j < NPOINT; ++j) {
        const f4 lx4 = (f4){lx, lx, lx, lx};
        const f4 ly4 = (f4){ly, ly, ly, ly};
        const f4 lz4 = (f4){lz, lz, lz, lz};

        // --- update temps vs pivot; 4 rotating max accumulators ---
        float m0 = 0.0f, m1 = 0.0f, m2 = 0.0f, m3 = 0.0f;
#define UPD(g) { f4 dx = X##g - lx4;                                        \
                 f4 dy = Y##g - ly4;                                        \
                 f4 dz = Z##g - lz4;                                        \
                 f4 s  = (dx * dx + dy * dy) + dz * dz;   /* numpy order */ \
                 T##g.x = fminf(T##g.x, s.x);                               \
                 T##g.y = fminf(T##g.y, s.y);                               \
                 T##g.z = fminf(T##g.z, s.z);                               \
                 T##g.w = fminf(T##g.w, s.w);                               \
                 if (((g) & 1) == 0) {                                      \
                     m0 = fmaxf(m0, fmaxf(T##g.x, T##g.y));  /* v_max3 */   \
                     m1 = fmaxf(m1, fmaxf(T##g.z, T##g.w));                 \
                 } else {                                                   \
                     m2 = fmaxf(m2, fmaxf(T##g.x, T##g.y));                 \
                     m3 = fmaxf(m3, fmaxf(T##g.z, T##g.w));                 \
                 } }
        REP8(UPD)
#undef UPD
        float vmax = fmaxf(fmaxf(m0, m1), fmaxf(m2, m3));

        // --- wave max (all lanes end with wave max) ---
#pragma unroll
        for (int off = 32; off >= 1; off >>= 1)
            vmax = fmaxf(vmax, __shfl_xor(vmax, off));

        // --- every wave scans its own registers for its wave-max index ---
        int cand = N;
#define SCANG(g) { const int b4 = 4 * ((g) * NT + t);          \
                   cand = (T##g.w == vmax) ? b4 + 3 : cand;    \
                   cand = (T##g.z == vmax) ? b4 + 2 : cand;    \
                   cand = (T##g.y == vmax) ? b4 + 1 : cand;    \
                   cand = (T##g.x == vmax) ? b4     : cand; }
        REP8R(SCANG)                           // descending -> lowest idx wins
#undef SCANG

        // --- single packed atomic: max distance, lowest index on ties ---
        // dist bits monotone (T >= 0); larger (N-cand) == smaller cand.
        if (cand < N)
            atomicMax(&s_key[j],
                      ((unsigned long long)__float_as_uint(vmax) << 32) |
                      (unsigned)(N - cand));
        __syncthreads();                       // the only barrier per iter

        const unsigned long long K = s_key[j];
        const int sel =
            __builtin_amdgcn_readfirstlane(N - (int)(unsigned)(K & 0xffffffffu));
        lx = px[sel];                          // uniform -> scalar load (L2)
        ly = py[sel];
        lz = pz[sel];
        if (t == 0) { outx[j] = lx; outy[j] = ly; outz[j] = lz; }
    }
}

extern "C" void kernel_launch(void* const* d_in, const int* in_sizes, int n_in,
                              void* d_out, int out_size, void* d_ws, size_t ws_size,
                              hipStream_t stream) {
    // d_in[0]: points_xyz (B,N,3) — unused
    // d_in[1]: points_xyz_t (B,3,N)
    // d_in[2]: features_with_xyz (B,67,N) — unused
    const float* pts_t = (const float*)d_in[1];
    float* out = (float*)d_out;
    fps_kernel<<<BATCH, NT, 0, stream>>>(pts_t, out);
}